// Round 13
// baseline (290.559 us; speedup 1.0000x reference)
//
#include <hip/hip_runtime.h>

#define NN 50000
#define NE 800000
#define DK 128            // feature dim into layers 0/1
#define NN_PAD 50048      // multiple of 128 for GEMM row blocks

// raw windowed adjacency: 7 src-windows (win = src>>13), 20 ushort slots each
#define SW 7
#define SUBCAP 20
#define RAWCAP 144        // ushorts per node (288B row)
// compacted dense window-ordered list
#define CAP2 64

// counter spread: each (node,window) counter on its own 32B sector
// (R12 theory: 64 atomics/128B-line serialize at ~12ns each => ~50us floor)
#define CSH 3             // counter index = ((node<<3)+win) << CSH
#define WCUR_INTS (NN * 8 * (1 << CSH))

// aggregate: all blocks co-resident, grid-stride sweeps -> loose lockstep over
// window-sorted dense lists => rolling L2-resident src band
#define AGG_BLOCKS 1568

typedef __attribute__((ext_vector_type(8))) short bf16x8;
typedef __attribute__((ext_vector_type(4))) float f32x4;
typedef __attribute__((ext_vector_type(2))) int   i32x2;
typedef __attribute__((ext_vector_type(4))) int   i32x4;
typedef __attribute__((ext_vector_type(4))) unsigned u32x4;
typedef __attribute__((ext_vector_type(8))) unsigned short u16x8;

__device__ inline unsigned short f2bf(float f) {
    unsigned u = __builtin_bit_cast(unsigned, f);
    u = (u + 0x7FFFu + ((u >> 16) & 1u)) >> 16;
    return (unsigned short)u;
}
__device__ inline float bfhi2f(unsigned u) {
    return __builtin_bit_cast(float, u & 0xFFFF0000u);
}
__device__ inline float bflo2f(unsigned u) {
    return __builtin_bit_cast(float, u << 16);
}
__device__ inline int clampn(int v) {           // ushort ids >= 0 already
    return v >= NN ? NN - 1 : v;
}
__device__ inline void acc16(float* acc, u32x4 v) {
    acc[0] += bflo2f(v.x); acc[1] += bfhi2f(v.x);
    acc[2] += bflo2f(v.y); acc[3] += bfhi2f(v.y);
    acc[4] += bflo2f(v.z); acc[5] += bfhi2f(v.z);
    acc[6] += bflo2f(v.w); acc[7] += bfhi2f(v.w);
}

// ---------------------------------------------------------------- setup

// vectorized grid-stride zero (u32x4), for the 12.8MB spread counter region
__global__ __launch_bounds__(256) void zero_vec(u32x4* __restrict__ p, int n4) {
    u32x4 z = {0u, 0u, 0u, 0u};
    for (int i = blockIdx.x * 256 + threadIdx.x; i < n4; i += gridDim.x * 256)
        p[i] = z;
}

// Single-pass windowed fill: 2 edges/thread, 2 independent atomic chains.
// Counters spread 32B apart => ~9 atomics/line instead of ~64.
__global__ __launch_bounds__(256) void fill_direct(const int* __restrict__ src,
                                                   const int* __restrict__ dst,
                                                   int* __restrict__ wcur,
                                                   unsigned short* __restrict__ eidxraw) {
    int e = (blockIdx.x * 256 + threadIdx.x) * 2;
    if (e >= NE) return;       // NE % 2 == 0
    i32x2 d2 = __builtin_nontemporal_load((const i32x2*)(dst + e));
    i32x2 s2 = __builtin_nontemporal_load((const i32x2*)(src + e));
    #pragma unroll
    for (int k = 0; k < 2; ++k) {
        int d = d2[k], s = s2[k];
        int win = s >> 13;                         // 0..6
        int slot = atomicAdd(&wcur[((d << 3) + win) << CSH], 1);
        if (slot < SUBCAP)
            eidxraw[d * RAWCAP + win * SUBCAP + slot] = (unsigned short)s;
    }
}

// compact windowed sub-lists into dense src-window-ordered lists of <=64
// (dense lists restore gather ILP — R11 lesson). One wave per node; emits deg.
__global__ __launch_bounds__(256) void compact(const int* __restrict__ wcur,
                                               const unsigned short* __restrict__ eidxraw,
                                               unsigned short* __restrict__ eidx2,
                                               int* __restrict__ deg) {
    int node = blockIdx.x * 4 + (threadIdx.x >> 6);
    int lane = threadIdx.x & 63;
    if (node >= NN) return;
    int c[SW], o[SW];
    int run = 0, dt = 0;
    #pragma unroll
    for (int w = 0; w < SW; ++w) {
        int cw = wcur[((node << 3) + w) << CSH];
        dt += cw;
        cw = (cw < SUBCAP) ? cw : SUBCAP;
        c[w] = cw; o[w] = run; run += cw;
    }
    if (lane == 0) deg[node] = dt;
    const unsigned short* rawp = eidxraw + (size_t)node * RAWCAP;
    unsigned short*       outp = eidx2   + (size_t)node * CAP2;
    for (int s = lane; s < SW * SUBCAP; s += 64) {
        int w = s / SUBCAP, j = s - w * SUBCAP;
        if (j < c[w]) {
            int dp = o[w] + j;
            if (dp < CAP2) outp[dp] = rawp[w * SUBCAP + j];
        }
    }
}

// ---------------------------------------------------------------- fused setup
// One dispatch: x->bf16 convert + all four weight packs (block-range branch).
#define CONV_BLK 3125                 // NN*DK/8/256, exact
#define PD_BLK   16                   // dual-pack blocks (N=128)

__device__ inline void pack_dual_blk(const float* Wl, const float* Wr,
                                     unsigned short* Wpack, int bid, int tid) {
    int t = bid * 256 + tid;          // < 4096
    int l  = t & 63;
    int ks = (t >> 6) & 7;
    int nt = t >> 9;
    int n  = nt * 16 + (l & 15);
    int kb = ks * 32 + (l >> 4) * 8;
    union { unsigned short us[8]; u32x4 u4; } o;
    #pragma unroll
    for (int j = 0; j < 8; ++j) {
        int k = kb + j;
        float w = (k < 128) ? Wl[k * 128 + n] : Wr[(k - 128) * 128 + n];
        o.us[j] = f2bf(w);
    }
    *(u32x4*)(Wpack + (size_t)t * 8) = o.u4;
}
__device__ inline void pack_single_blk(const float* W, unsigned short* Wpack,
                                       int bid, int tid) {
    int t = bid * 256 + tid;          // < 1024
    int l  = t & 63;
    int ks = (t >> 6) & 3;
    int nt = t >> 8;
    int n  = nt * 16 + (l & 15);
    int kb = ks * 32 + (l >> 4) * 8;
    union { unsigned short us[8]; u32x4 u4; } o;
    #pragma unroll
    for (int j = 0; j < 8; ++j) o.us[j] = f2bf(W[(kb + j) * 64 + n]);
    *(u32x4*)(Wpack + (size_t)t * 8) = o.u4;
}

__global__ __launch_bounds__(256) void setup_fused(const float* __restrict__ x,
                                                   unsigned short* __restrict__ xb,
                                                   const float* __restrict__ Wl0,
                                                   const float* __restrict__ Wr0,
                                                   unsigned short* __restrict__ Wp0,
                                                   const float* __restrict__ Wl1,
                                                   const float* __restrict__ Wr1,
                                                   unsigned short* __restrict__ Wp1,
                                                   const float* __restrict__ Wl2,
                                                   unsigned short* __restrict__ Wp2l,
                                                   const float* __restrict__ Wr2,
                                                   unsigned short* __restrict__ Wp2r) {
    int b = blockIdx.x, tid = threadIdx.x;
    if (b < CONV_BLK) {
        long long i = (long long)(b * 256 + tid) * 8;
        f32x4 a = __builtin_nontemporal_load((const f32x4*)(x + i));
        f32x4 c = __builtin_nontemporal_load((const f32x4*)(x + i + 4));
        union { unsigned short us[8]; u32x4 u4; } o;
        o.us[0] = f2bf(a.x); o.us[1] = f2bf(a.y); o.us[2] = f2bf(a.z); o.us[3] = f2bf(a.w);
        o.us[4] = f2bf(c.x); o.us[5] = f2bf(c.y); o.us[6] = f2bf(c.z); o.us[7] = f2bf(c.w);
        *(u32x4*)(xb + i) = o.u4;
    } else if (b < CONV_BLK + PD_BLK) {
        pack_dual_blk(Wl0, Wr0, Wp0, b - CONV_BLK, tid);
    } else if (b < CONV_BLK + 2 * PD_BLK) {
        pack_dual_blk(Wl1, Wr1, Wp1, b - CONV_BLK - PD_BLK, tid);
    } else if (b < CONV_BLK + 2 * PD_BLK + 4) {
        pack_single_blk(Wl2, Wp2l, b - CONV_BLK - 2 * PD_BLK, tid);
    } else {
        pack_single_blk(Wr2, Wp2r, b - CONV_BLK - 2 * PD_BLK - 4, tid);
    }
}
#define SETUP_BLKS (CONV_BLK + 2 * PD_BLK + 8)

// ---------------------------------------------------------------- aggregation (bf16)
// Dense window-ordered ushort lists, 8-deep gather unroll (u16x8 index loads).
// S = 16B-chunks per feature row (16 -> 128 dims, 8 -> 64 dims).
template <int S>
__global__ __launch_bounds__(256) void aggregate(const unsigned short* __restrict__ h,
                                                 const unsigned short* __restrict__ eidx2,
                                                 const int* __restrict__ deg,
                                                 unsigned short* __restrict__ agg) {
    constexpr int NPB = 256 / S;          // nodes per block
    int g    = threadIdx.x / S;
    int lane = threadIdx.x % S;
    const u32x4* h4 = (const u32x4*)h;
    for (int base = 0; base < NN; base += AGG_BLOCKS * NPB) {
        int node = base + blockIdx.x * NPB + g;
        if (node >= NN) continue;
        int d   = deg[node];
        int cap = (d < CAP2) ? d : CAP2;
        const unsigned short* el = eidx2 + (size_t)node * CAP2;  // 128B aligned
        float acc[8] = {0.f, 0.f, 0.f, 0.f, 0.f, 0.f, 0.f, 0.f};
        int j = 0;
        for (; j + 7 < cap; j += 8) {
            u16x8 i8 = *(const u16x8*)(el + j);      // 16B aligned (j%8==0)
            u32x4 v[8];
            #pragma unroll
            for (int q = 0; q < 8; ++q)
                v[q] = h4[(size_t)clampn((int)i8[q]) * S + lane];
            #pragma unroll
            for (int q = 0; q < 8; ++q) acc16(acc, v[q]);
        }
        for (; j + 3 < cap; j += 4) {
            u32x4 v[4];
            #pragma unroll
            for (int q = 0; q < 4; ++q)
                v[q] = h4[(size_t)clampn((int)el[j + q]) * S + lane];
            #pragma unroll
            for (int q = 0; q < 4; ++q) acc16(acc, v[q]);
        }
        for (; j < cap; ++j)
            acc16(acc, h4[(size_t)clampn((int)el[j]) * S + lane]);
        float r = 1.0f / (float)(d > 0 ? d : 1);
        union { unsigned short us[8]; u32x4 u4; } o;
        #pragma unroll
        for (int k = 0; k < 8; ++k) o.us[k] = f2bf(acc[k] * r);
        __builtin_nontemporal_store(o.u4, (u32x4*)agg + (size_t)node * S + lane);
    }
}

// ---------------------------------------------------------------- MFMA GEMMs

// layers 0/1: out = act( agg@Wl + h@Wr + b ), K=256, N=128, bf16 out
template <int N, bool RELU, bool OUT_BF16>
__global__ __launch_bounds__(256) void gemm_mfma(const unsigned short* __restrict__ agg,
                                                 const unsigned short* __restrict__ h,
                                                 const unsigned short* __restrict__ Wpack,
                                                 const float* __restrict__ bias,
                                                 void* __restrict__ outp) {
    __shared__ unsigned short Wlds[N * 256];
    int tid = threadIdx.x;
    {
        const u32x4* wg = (const u32x4*)Wpack;
        u32x4* wl = (u32x4*)Wlds;
        #pragma unroll
        for (int i = tid; i < N * 32; i += 256) wl[i] = wg[i];
    }
    __syncthreads();

    int wave = tid >> 6, lane = tid & 63;
    int m = lane & 15, quad = lane >> 4;
    int row0 = blockIdx.x * 128 + wave * 16;     // second tile at row0 + 64

    const unsigned short* arow = agg + (size_t)(row0 + m) * 128 + quad * 8;
    const unsigned short* hrow = h   + (size_t)(row0 + m) * 128 + quad * 8;

    f32x4 acc0[N / 16] = {};
    f32x4 acc1[N / 16] = {};
    #pragma unroll
    for (int ks = 0; ks < 8; ++ks) {
        const unsigned short* s = (ks < 4) ? (arow + ks * 32) : (hrow + (ks - 4) * 32);
        bf16x8 a0 = *(const bf16x8*)s;
        bf16x8 a1 = *(const bf16x8*)(s + 64 * 128);
        #pragma unroll
        for (int nt = 0; nt < N / 16; ++nt) {
            bf16x8 b = *(const bf16x8*)&Wlds[((nt * 8 + ks) * 64 + lane) * 8];
            acc0[nt] = __builtin_amdgcn_mfma_f32_16x16x32_bf16(a0, b, acc0[nt], 0, 0, 0);
            acc1[nt] = __builtin_amdgcn_mfma_f32_16x16x32_bf16(a1, b, acc1[nt], 0, 0, 0);
        }
    }

    #pragma unroll
    for (int t = 0; t < 2; ++t) {
        #pragma unroll
        for (int nt = 0; nt < N / 16; ++nt) {
            int n = nt * 16 + m;
            float bv = bias[n];
            #pragma unroll
            for (int r = 0; r < 4; ++r) {
                int row = row0 + t * 64 + quad * 4 + r;
                if (row < NN) {
                    float v = (t == 0 ? acc0[nt][r] : acc1[nt][r]) + bv;
                    if (RELU) v = fmaxf(v, 0.f);
                    if (OUT_BF16)
                        ((unsigned short*)outp)[(size_t)row * N + n] = f2bf(v);
                    else
                        ((float*)outp)[(size_t)row * N + n] = v;
                }
            }
        }
    }
}

// P = h @ W (K=128, N=64), bf16 out, no bias/act  — layer-2 "pre-GEMM"
// (agg(h)@Wl2 == agg(h@Wl2): aggregate in 64-dim space -> half gather bytes)
__global__ __launch_bounds__(256) void gemm_single(const unsigned short* __restrict__ h,
                                                   const unsigned short* __restrict__ Wpack,
                                                   unsigned short* __restrict__ P) {
    __shared__ unsigned short Wlds[64 * 128];
    int tid = threadIdx.x;
    {
        const u32x4* wg = (const u32x4*)Wpack;
        u32x4* wl = (u32x4*)Wlds;
        #pragma unroll
        for (int i = tid; i < 1024; i += 256) wl[i] = wg[i];
    }
    __syncthreads();

    int wave = tid >> 6, lane = tid & 63;
    int m = lane & 15, quad = lane >> 4;
    int row0 = blockIdx.x * 128 + wave * 16;

    const unsigned short* hrow = h + (size_t)(row0 + m) * 128 + quad * 8;

    f32x4 acc0[4] = {};
    f32x4 acc1[4] = {};
    #pragma unroll
    for (int ks = 0; ks < 4; ++ks) {
        bf16x8 a0 = *(const bf16x8*)(hrow + ks * 32);
        bf16x8 a1 = *(const bf16x8*)(hrow + ks * 32 + 64 * 128);
        #pragma unroll
        for (int nt = 0; nt < 4; ++nt) {
            bf16x8 b = *(const bf16x8*)&Wlds[((nt * 4 + ks) * 64 + lane) * 8];
            acc0[nt] = __builtin_amdgcn_mfma_f32_16x16x32_bf16(a0, b, acc0[nt], 0, 0, 0);
            acc1[nt] = __builtin_amdgcn_mfma_f32_16x16x32_bf16(a1, b, acc1[nt], 0, 0, 0);
        }
    }

    #pragma unroll
    for (int t = 0; t < 2; ++t) {
        #pragma unroll
        for (int nt = 0; nt < 4; ++nt) {
            int n = nt * 16 + m;
            #pragma unroll
            for (int r = 0; r < 4; ++r) {
                int row = row0 + t * 64 + quad * 4 + r;
                if (row < NN)
                    P[(size_t)row * 64 + n] = f2bf(t == 0 ? acc0[nt][r] : acc1[nt][r]);
            }
        }
    }
}

// out = h @ Wr2 + aggP + bias (K=128, N=64), fp32 out — layer-2 final
__global__ __launch_bounds__(256) void gemm_final(const unsigned short* __restrict__ h,
                                                  const unsigned short* __restrict__ Wpack,
                                                  const float* __restrict__ bias,
                                                  const unsigned short* __restrict__ aggP,
                                                  float* __restrict__ outp) {
    __shared__ unsigned short Wlds[64 * 128];
    int tid = threadIdx.x;
    {
        const u32x4* wg = (const u32x4*)Wpack;
        u32x4* wl = (u32x4*)Wlds;
        #pragma unroll
        for (int i = tid; i < 1024; i += 256) wl[i] = wg[i];
    }
    __syncthreads();

    int wave = tid >> 6, lane = tid & 63;
    int m = lane & 15, quad = lane >> 4;
    int row0 = blockIdx.x * 128 + wave * 16;

    const unsigned short* hrow = h + (size_t)(row0 + m) * 128 + quad * 8;

    f32x4 acc0[4] = {};
    f32x4 acc1[4] = {};
    #pragma unroll
    for (int ks = 0; ks < 4; ++ks) {
        bf16x8 a0 = *(const bf16x8*)(hrow + ks * 32);
        bf16x8 a1 = *(const bf16x8*)(hrow + ks * 32 + 64 * 128);
        #pragma unroll
        for (int nt = 0; nt < 4; ++nt) {
            bf16x8 b = *(const bf16x8*)&Wlds[((nt * 4 + ks) * 64 + lane) * 8];
            acc0[nt] = __builtin_amdgcn_mfma_f32_16x16x32_bf16(a0, b, acc0[nt], 0, 0, 0);
            acc1[nt] = __builtin_amdgcn_mfma_f32_16x16x32_bf16(a1, b, acc1[nt], 0, 0, 0);
        }
    }

    #pragma unroll
    for (int t = 0; t < 2; ++t) {
        #pragma unroll
        for (int nt = 0; nt < 4; ++nt) {
            int n = nt * 16 + m;
            float bv = bias[n];
            #pragma unroll
            for (int r = 0; r < 4; ++r) {
                int row = row0 + t * 64 + quad * 4 + r;
                if (row < NN) {
                    float av = bflo2f((unsigned)aggP[(size_t)row * 64 + n]);
                    outp[(size_t)row * 64 + n] =
                        (t == 0 ? acc0[nt][r] : acc1[nt][r]) + bv + av;
                }
            }
        }
    }
}

// ---------------------------------------------------------------- launch

static inline size_t align256(size_t x) { return (x + 255) & ~(size_t)255; }

extern "C" void kernel_launch(void* const* d_in, const int* in_sizes, int n_in,
                              void* d_out, int out_size, void* d_ws, size_t ws_size,
                              hipStream_t stream) {
    const float* x    = (const float*)d_in[0];
    const int*   ei   = (const int*)d_in[1];
    const int*   esrc = ei;
    const int*   edst = ei + NE;
    const float* Wl0 = (const float*)d_in[2];
    const float* bl0 = (const float*)d_in[3];
    const float* Wr0 = (const float*)d_in[4];
    const float* Wl1 = (const float*)d_in[5];
    const float* bl1 = (const float*)d_in[6];
    const float* Wr1 = (const float*)d_in[7];
    const float* Wl2 = (const float*)d_in[8];
    const float* bl2 = (const float*)d_in[9];
    const float* Wr2 = (const float*)d_in[10];

    char* ws = (char*)d_ws;
    size_t off = 0;
    int* wcur = (int*)(ws + off);               off = align256(off + (size_t)WCUR_INTS * 4);
    unsigned short* eidxraw = (unsigned short*)(ws + off);
    off = align256(off + (size_t)NN * RAWCAP * 2);
    unsigned short* eidx2 = (unsigned short*)(ws + off);
    off = align256(off + (size_t)NN * CAP2 * 2);
    int* deg = (int*)(ws + off);                off = align256(off + (size_t)NN * 4);
    unsigned short* xb   = (unsigned short*)(ws + off); off = align256(off + (size_t)NN_PAD * DK * 2);
    unsigned short* bAgg = (unsigned short*)(ws + off); off = align256(off + (size_t)NN_PAD * DK * 2);
    unsigned short* bH   = (unsigned short*)(ws + off); off = align256(off + (size_t)NN_PAD * DK * 2);
    unsigned short* P2   = (unsigned short*)(ws + off); off = align256(off + (size_t)NN_PAD * 64 * 2);
    unsigned short* aggP = (unsigned short*)(ws + off); off = align256(off + (size_t)NN_PAD * 64 * 2);
    unsigned short* Wp0  = (unsigned short*)(ws + off); off = align256(off + (size_t)256 * 128 * 2);
    unsigned short* Wp1  = (unsigned short*)(ws + off); off = align256(off + (size_t)256 * 128 * 2);
    unsigned short* Wp2l = (unsigned short*)(ws + off); off = align256(off + (size_t)128 * 64 * 2);
    unsigned short* Wp2r = (unsigned short*)(ws + off); off = align256(off + (size_t)128 * 64 * 2);

    // ---- adjacency build: spread-counter zero -> windowed fill -> compact ----
    zero_vec<<<1024, 256, 0, stream>>>((u32x4*)wcur, WCUR_INTS / 4);
    fill_direct<<<(NE / 2 + 255) / 256, 256, 0, stream>>>(esrc, edst, wcur, eidxraw);
    compact<<<(NN + 3) / 4, 256, 0, stream>>>(wcur, eidxraw, eidx2, deg);

    // ---- fused setup: x -> bf16 + all weight packs in one dispatch ----
    setup_fused<<<SETUP_BLKS, 256, 0, stream>>>(x, xb, Wl0, Wr0, Wp0,
                                                Wl1, Wr1, Wp1,
                                                Wl2, Wp2l, Wr2, Wp2r);

    const int GEMM_GRID = NN_PAD / 128;

    // ---- layer 0: xb -> bH (relu) ----
    aggregate<16><<<AGG_BLOCKS, 256, 0, stream>>>(xb, eidx2, deg, bAgg);
    gemm_mfma<128, true, true><<<GEMM_GRID, 256, 0, stream>>>(bAgg, xb, Wp0, bl0, bH);

    // ---- layer 1: bH -> xb (relu; xb dead after this GEMM reads it) ----
    aggregate<16><<<AGG_BLOCKS, 256, 0, stream>>>(bH, eidx2, deg, bAgg);
    gemm_mfma<128, true, true><<<GEMM_GRID, 256, 0, stream>>>(bAgg, bH, Wp1, bl1, xb);

    // ---- layer 2 (restructured): P2 = xb@Wl2; aggP = agg(P2); out = xb@Wr2 + aggP + b ----
    gemm_single<<<GEMM_GRID, 256, 0, stream>>>(xb, Wp2l, P2);
    aggregate<8><<<AGG_BLOCKS, 256, 0, stream>>>(P2, eidx2, deg, aggP);
    gemm_final<<<GEMM_GRID, 256, 0, stream>>>(xb, Wp2r, bl2, aggP, (float*)d_out);
}